// Round 8
// baseline (36.044 us; speedup 1.0000x reference)
//
#include <hip/hip_runtime.h>
#include <hip/hip_bf16.h>

#define B_N 32768
#define H_N 768
#define L_N 10
#define M_BLK 32               // samples per block (2 m-tiles x 16 rows)
#define NCOL 32                // output cols padded 30 -> 32
#define NSLOT 96               // 768 / 8 k-slots
#define KQ_STEPS 6             // ksteps per K-quarter (768 / 32 / 4)

typedef __attribute__((ext_vector_type(8))) short short8v;
typedef __attribute__((ext_vector_type(4))) float float4v;

// 8x f32 -> bf16 via packed HW converts (compiler emits v_cvt_pk_bf16_f32)
static __device__ __forceinline__ short8v cvt8(const float4 f0, const float4 f1) {
    union { __hip_bfloat162 h[4]; short8v v; } u;
    u.h[0] = __float22bfloat162_rn(make_float2(f0.x, f0.y));
    u.h[1] = __float22bfloat162_rn(make_float2(f0.z, f0.w));
    u.h[2] = __float22bfloat162_rn(make_float2(f1.x, f1.y));
    u.h[3] = __float22bfloat162_rn(make_float2(f1.z, f1.w));
    return u.v;
}

// ---- prep: f32 weights -> bf16 fragment table wb[slot][col][8] in d_ws ----
__global__ __launch_bounds__(256) void prep_weights(
    const float* __restrict__ w1, const float* __restrict__ w2,
    const float* __restrict__ w3, short* __restrict__ wb)
{
    const int idx = blockIdx.x * 256 + threadIdx.x;   // 0 .. 96*32-1
    if (idx >= NSLOT * NCOL) return;
    const int slot = idx >> 5;          // k/8
    const int c    = idx & 31;          // col
    short8v v;
    if (c < 30) {
        const float* src = (c < 10) ? (w1 + c * H_N)
                         : (c < 20) ? (w2 + (c - 10) * H_N)
                                    : (w3 + (c - 20) * H_N);
        const float4 f0 = *reinterpret_cast<const float4*>(src + slot * 8);
        const float4 f1 = *reinterpret_cast<const float4*>(src + slot * 8 + 4);
        v = cvt8(f0, f1);
    } else {
        v = short8v{0, 0, 0, 0, 0, 0, 0, 0};   // padding (d_ws is poisoned)
    }
    *reinterpret_cast<short8v*>(wb + idx * 8) = v;
}

// ---- main: MFMA grouped-GEMM + CE, B-frags from L2-resident table --------
__global__ __launch_bounds__(512) void fused_mfma_ce(
    const float* __restrict__ hs, const short* __restrict__ wb,
    const float* __restrict__ b1v, const float* __restrict__ b2v,
    const float* __restrict__ b3v,
    const int* __restrict__ groups, const int* __restrict__ labels,
    float* __restrict__ out)
{
    __shared__ float slog[4][M_BLK][33];   // 16,896 B (K-quarter partials)

    const int t  = threadIdx.x;
    const int w  = t >> 6;      // wave 0..7
    const int mt = w & 1;       // m-tile 0..1
    const int kq = w >> 1;      // K-quarter 0..3
    const int l  = t & 63;
    const int cq = l & 15;      // fragment row/col within 16
    const int bq = l >> 4;      // k-subslot 0..3

    const int m0 = blockIdx.x * M_BLK + mt * 16;
    const float* aptr = hs + (size_t)(m0 + cq) * H_N + kq * (H_N / 4) + bq * 8;
    const short* bb0 = wb + (((kq * KQ_STEPS * 4 + bq) * NCOL) + cq) * 8;
    const short* bb1 = bb0 + 16 * 8;   // cols 16..31

    float4v acc0 = {0.f, 0.f, 0.f, 0.f};
    float4v acc1 = {0.f, 0.f, 0.f, 0.f};

    #pragma unroll 2
    for (int ks = 0; ks < KQ_STEPS; ++ks) {
        const float4 f0 = *reinterpret_cast<const float4*>(aptr + ks * 32);
        const float4 f1 = *reinterpret_cast<const float4*>(aptr + ks * 32 + 4);
        const short8v b0 = *reinterpret_cast<const short8v*>(bb0 + ks * (NCOL * 4 * 8));
        const short8v b1 = *reinterpret_cast<const short8v*>(bb1 + ks * (NCOL * 4 * 8));
        const short8v a = cvt8(f0, f1);
        acc0 = __builtin_amdgcn_mfma_f32_16x16x32_bf16(a, b0, acc0, 0, 0, 0);
        acc1 = __builtin_amdgcn_mfma_f32_16x16x32_bf16(a, b1, acc1, 0, 0, 0);
    }

    // ---- epilogue: K-quarter partial logits -> LDS, combine, CE, reduce --
    #pragma unroll
    for (int r = 0; r < 4; ++r) {        // D row = 4*bq + r, col = cq (+16)
        slog[kq][mt * 16 + bq * 4 + r][cq]      = acc0[r];
        slog[kq][mt * 16 + bq * 4 + r][cq + 16] = acc1[r];
    }
    __syncthreads();

    float nll = 0.f;
    if (t < M_BLK) {
        const int s   = blockIdx.x * M_BLK + t;
        const int g   = groups[s];
        const int lab = labels[s];
        const float* bp = (g == 0) ? b1v : ((g == 1) ? b2v : b3v);
        float lv[L_N];
        #pragma unroll
        for (int j = 0; j < L_N; ++j)
            lv[j] = slog[0][t][g * 10 + j] + slog[1][t][g * 10 + j]
                  + slog[2][t][g * 10 + j] + slog[3][t][g * 10 + j] + bp[j];
        float m = lv[0];
        #pragma unroll
        for (int j = 1; j < L_N; ++j) m = fmaxf(m, lv[j]);
        float sum = 0.f;
        #pragma unroll
        for (int j = 0; j < L_N; ++j) sum += expf(lv[j] - m);
        float sel = lv[0];
        #pragma unroll
        for (int j = 1; j < L_N; ++j) sel = (lab == j) ? lv[j] : sel;
        nll = (m + logf(sum)) - sel;
    }
    if (t < 64) {
        #pragma unroll
        for (int off = 32; off > 0; off >>= 1)
            nll += __shfl_down(nll, off, 64);
        if (t == 0) atomicAdd(out, nll * (1.0f / (float)B_N));
    }
}

extern "C" void kernel_launch(void* const* d_in, const int* in_sizes, int n_in,
                              void* d_out, int out_size, void* d_ws, size_t ws_size,
                              hipStream_t stream) {
    const float* hs  = (const float*)d_in[0];
    const float* w1  = (const float*)d_in[1];
    const float* b1v = (const float*)d_in[2];
    const float* w2  = (const float*)d_in[3];
    const float* b2v = (const float*)d_in[4];
    const float* w3  = (const float*)d_in[5];
    const float* b3v = (const float*)d_in[6];
    const int* groups = (const int*)d_in[7];
    const int* labels = (const int*)d_in[8];
    float* out = (float*)d_out;
    short* wb  = (short*)d_ws;                        // 49,152 B table

    hipMemsetAsync(out, 0, sizeof(float), stream);
    prep_weights<<<(NSLOT * NCOL + 255) / 256, 256, 0, stream>>>(w1, w2, w3, wb);
    fused_mfma_ce<<<B_N / M_BLK, 512, 0, stream>>>(
        hs, wb, b1v, b2v, b3v, groups, labels, out);
}

// Round 9
// 33.411 us; speedup vs baseline: 1.0788x; 1.0788x over previous
//
#include <hip/hip_runtime.h>
#include <hip/hip_bf16.h>

#define B_N 32768
#define H_N 768
#define L_N 10
#define M_BLK 64               // samples per block (4 m-tiles x 16 rows)
#define NCOL 32                // output cols padded 30 -> 32
#define NSLOT 96               // 768 / 8 k-slots
#define KH_STEPS 12            // ksteps per K-half (768 / 32 / 2)

typedef __attribute__((ext_vector_type(8))) short short8v;
typedef __attribute__((ext_vector_type(4))) float float4v;

// 8x f32 -> bf16 via packed HW converts (compiler emits v_cvt_pk_bf16_f32)
static __device__ __forceinline__ short8v cvt8(const float4 f0, const float4 f1) {
    union { __hip_bfloat162 h[4]; short8v v; } u;
    u.h[0] = __float22bfloat162_rn(make_float2(f0.x, f0.y));
    u.h[1] = __float22bfloat162_rn(make_float2(f0.z, f0.w));
    u.h[2] = __float22bfloat162_rn(make_float2(f1.x, f1.y));
    u.h[3] = __float22bfloat162_rn(make_float2(f1.z, f1.w));
    return u.v;
}

__global__ __launch_bounds__(512) void fused_mfma_ce(
    const float* __restrict__ hs,
    const float* __restrict__ w1, const float* __restrict__ b1v,
    const float* __restrict__ w2, const float* __restrict__ b2v,
    const float* __restrict__ w3, const float* __restrict__ b3v,
    const int* __restrict__ groups, const int* __restrict__ labels,
    float* __restrict__ out)
{
    // weights bf16, k-slot-major: w[c][k] at wlds[((k/8)*NCOL + c)*8 + k%8]
    __shared__ __align__(16) short wlds[NSLOT * NCOL * 8];   // 48 KB

    const int t  = threadIdx.x;
    const int w  = t >> 6;      // wave 0..7
    const int mt = w & 3;       // m-tile 0..3
    const int kh = w >> 2;      // K-half 0..1
    const int l  = t & 63;
    const int cq = l & 15;      // fragment row/col within 16
    const int bq = l >> 4;      // k-chunk group 0..3

    // ---- one-time weight stage: f32 -> bf16 LDS via packed cvt ----------
    for (int idx = t; idx < NCOL * NSLOT; idx += 512) {
        const int c    = idx / NSLOT;
        const int slot = idx % NSLOT;
        short8v v;
        if (c < 30) {
            const float* src = (c < 10) ? (w1 + c * H_N)
                             : (c < 20) ? (w2 + (c - 10) * H_N)
                                        : (w3 + (c - 20) * H_N);
            const float4 f0 = *reinterpret_cast<const float4*>(src + slot * 8);
            const float4 f1 = *reinterpret_cast<const float4*>(src + slot * 8 + 4);
            v = cvt8(f0, f1);
        } else {
            v = short8v{0, 0, 0, 0, 0, 0, 0, 0};
        }
        *reinterpret_cast<short8v*>(wlds + (slot * NCOL + c) * 8) = v;
    }
    __syncthreads();

    // ---- K-half loop: A direct global->frag (packed cvt); B from LDS ----
    const int m0 = blockIdx.x * M_BLK + mt * 16;
    const float* aptr = hs + (size_t)(m0 + cq) * H_N + kh * (H_N / 2) + bq * 8;
    const short* bb0 = wlds + (((kh * KH_STEPS * 4 + bq) * NCOL) + cq) * 8;
    const short* bb1 = bb0 + 16 * 8;   // cols 16..31

    float4v acc0 = {0.f, 0.f, 0.f, 0.f};
    float4v acc1 = {0.f, 0.f, 0.f, 0.f};

    #pragma unroll 6
    for (int ks = 0; ks < KH_STEPS; ++ks) {
        const float4 f0 = *reinterpret_cast<const float4*>(aptr + ks * 32);
        const float4 f1 = *reinterpret_cast<const float4*>(aptr + ks * 32 + 4);
        const short8v b0 = *reinterpret_cast<const short8v*>(bb0 + ks * (NCOL * 4 * 8));
        const short8v b1 = *reinterpret_cast<const short8v*>(bb1 + ks * (NCOL * 4 * 8));
        const short8v a = cvt8(f0, f1);
        acc0 = __builtin_amdgcn_mfma_f32_16x16x32_bf16(a, b0, acc0, 0, 0, 0);
        acc1 = __builtin_amdgcn_mfma_f32_16x16x32_bf16(a, b1, acc1, 0, 0, 0);
    }

    // ---- epilogue: K-half partial logits -> LDS, combine, CE, reduce -----
    __syncthreads();                     // all waves done reading wlds
    float (*slog)[M_BLK][33] = (float (*)[M_BLK][33])wlds;   // [2][64][33]
    #pragma unroll
    for (int r = 0; r < 4; ++r) {        // D row = 4*bq + r, col = cq (+16)
        slog[kh][mt * 16 + bq * 4 + r][cq]      = acc0[r];
        slog[kh][mt * 16 + bq * 4 + r][cq + 16] = acc1[r];
    }
    __syncthreads();

    float nll = 0.f;
    if (t < M_BLK) {
        const int s   = blockIdx.x * M_BLK + t;
        const int g   = groups[s];
        const int lab = labels[s];
        const float* bp = (g == 0) ? b1v : ((g == 1) ? b2v : b3v);
        float lv[L_N];
        #pragma unroll
        for (int j = 0; j < L_N; ++j)
            lv[j] = slog[0][t][g * 10 + j] + slog[1][t][g * 10 + j] + bp[j];
        float m = lv[0];
        #pragma unroll
        for (int j = 1; j < L_N; ++j) m = fmaxf(m, lv[j]);
        float sum = 0.f;
        #pragma unroll
        for (int j = 0; j < L_N; ++j) sum += expf(lv[j] - m);
        float sel = lv[0];
        #pragma unroll
        for (int j = 1; j < L_N; ++j) sel = (lab == j) ? lv[j] : sel;
        nll = (m + logf(sum)) - sel;
    }
    if (t < 64) {
        #pragma unroll
        for (int off = 32; off > 0; off >>= 1)
            nll += __shfl_down(nll, off, 64);
        if (t == 0) atomicAdd(out, nll * (1.0f / (float)B_N));
    }
}

extern "C" void kernel_launch(void* const* d_in, const int* in_sizes, int n_in,
                              void* d_out, int out_size, void* d_ws, size_t ws_size,
                              hipStream_t stream) {
    const float* hs  = (const float*)d_in[0];
    const float* w1  = (const float*)d_in[1];
    const float* b1v = (const float*)d_in[2];
    const float* w2  = (const float*)d_in[3];
    const float* b2v = (const float*)d_in[4];
    const float* w3  = (const float*)d_in[5];
    const float* b3v = (const float*)d_in[6];
    const int* groups = (const int*)d_in[7];
    const int* labels = (const int*)d_in[8];
    float* out = (float*)d_out;

    hipMemsetAsync(out, 0, sizeof(float), stream);
    fused_mfma_ce<<<B_N / M_BLK, 512, 0, stream>>>(
        hs, w1, b1v, w2, b2v, w3, b3v, groups, labels, out);
}